// Round 1
// baseline (61.195 us; speedup 1.0000x reference)
//
#include <hip/hip_runtime.h>

// Resample1d: out[b,c,h,w] = lerp of input1[b,c,h,:] at x = w + disp[b,h,w],
// zeroed where x outside [0, W-1].
// Shapes: input1 (B,C,H,W) f32, input2 (B,1,H,W) f32, out (B,C,H,W) f32.

#define B 4
#define C 64
#define H 256
#define W 512

__global__ __launch_bounds__(256) void resample1d_kernel(
    const float* __restrict__ in1,   // (B,C,H,W)
    const float* __restrict__ in2,   // (B,1,H,W)
    float* __restrict__ out)         // (B,C,H,W)
{
    const int HW = H * W;
    int idx = blockIdx.x * 256 + threadIdx.x;   // flat (b,h,w), exactly B*H*W threads
    int b  = idx / HW;
    int hw = idx - b * HW;
    int w  = hw & (W - 1);

    float disp = in2[idx];
    float x = (float)w + disp;
    bool valid = (x >= 0.0f) && (x <= (float)(W - 1));
    float x0 = floorf(x);
    float frac = x - x0;

    float x0c = fminf(fmaxf(x0,        0.0f), (float)(W - 1));
    float x1c = fminf(fmaxf(x0 + 1.0f, 0.0f), (float)(W - 1));
    int i0 = (int)x0c;
    int i1 = (int)x1c;
    float w0 = 1.0f - frac;
    float w1 = frac;

    const float* rowbase = in1 + (size_t)b * C * HW + (size_t)(hw - w); // b, c=0, h, 0
    float*       outp    = out + (size_t)b * C * HW + (size_t)hw;       // b, c=0, h, w

    #pragma unroll 8
    for (int c = 0; c < C; ++c) {
        float g0 = rowbase[(size_t)c * HW + i0];
        float g1 = rowbase[(size_t)c * HW + i1];
        float r  = w0 * g0 + w1 * g1;
        outp[(size_t)c * HW] = valid ? r : 0.0f;
    }
}

extern "C" void kernel_launch(void* const* d_in, const int* in_sizes, int n_in,
                              void* d_out, int out_size, void* d_ws, size_t ws_size,
                              hipStream_t stream) {
    const float* in1 = (const float*)d_in[0];
    const float* in2 = (const float*)d_in[1];
    float* out = (float*)d_out;

    int pixels = B * H * W;                 // 524288
    dim3 grid(pixels / 256), block(256);
    resample1d_kernel<<<grid, block, 0, stream>>>(in1, in2, out);
}

// Round 2
// 50.402 us; speedup vs baseline: 1.2141x; 1.2141x over previous
//
#include <hip/hip_runtime.h>

// Resample1d: out[b,c,h,w] = lerp of input1[b,c,h,:] at x = w + disp[b,h,w],
// zeroed where x outside [0, W-1].
// Shapes: input1 (B,C,H,W) f32, input2 (B,1,H,W) f32, out (B,C,H,W) f32.
//
// R2: latency-bound fix — split C across blockIdx.y (8 ch/thread -> 8x the
// waves for latency hiding), non-temporal stores (don't evict L3-resident
// input1 with the 131 MB write stream).

#define B 4
#define C 64
#define H 256
#define W 512
#define CCHUNK 8   // channels per thread

__global__ __launch_bounds__(256) void resample1d_kernel(
    const float* __restrict__ in1,   // (B,C,H,W)
    const float* __restrict__ in2,   // (B,1,H,W)
    float* __restrict__ out)         // (B,C,H,W)
{
    const int HW = H * W;
    int idx = blockIdx.x * 256 + threadIdx.x;   // flat (b,h,w)
    int b  = idx / HW;
    int hw = idx - b * HW;
    int w  = hw & (W - 1);
    int c0 = blockIdx.y * CCHUNK;

    float disp = in2[idx];
    float x = (float)w + disp;
    bool valid = (x >= 0.0f) && (x <= (float)(W - 1));
    float x0 = floorf(x);
    float frac = x - x0;

    float x0c = fminf(fmaxf(x0,        0.0f), (float)(W - 1));
    float x1c = fminf(fmaxf(x0 + 1.0f, 0.0f), (float)(W - 1));
    int i0 = (int)x0c;
    int i1 = (int)x1c;
    float w0 = valid ? (1.0f - frac) : 0.0f;
    float w1 = valid ? frac : 0.0f;

    const float* rowbase = in1 + (size_t)b * C * HW + (size_t)c0 * HW + (size_t)(hw - w);
    float*       outp    = out + (size_t)b * C * HW + (size_t)c0 * HW + (size_t)hw;

    float g0[CCHUNK], g1[CCHUNK];
    #pragma unroll
    for (int c = 0; c < CCHUNK; ++c) {
        g0[c] = rowbase[(size_t)c * HW + i0];
        g1[c] = rowbase[(size_t)c * HW + i1];
    }
    #pragma unroll
    for (int c = 0; c < CCHUNK; ++c) {
        float r = w0 * g0[c] + w1 * g1[c];
        __builtin_nontemporal_store(r, &outp[(size_t)c * HW]);
    }
}

extern "C" void kernel_launch(void* const* d_in, const int* in_sizes, int n_in,
                              void* d_out, int out_size, void* d_ws, size_t ws_size,
                              hipStream_t stream) {
    const float* in1 = (const float*)d_in[0];
    const float* in2 = (const float*)d_in[1];
    float* out = (float*)d_out;

    int pixels = B * H * W;                 // 524288
    dim3 grid(pixels / 256, C / CCHUNK), block(256);
    resample1d_kernel<<<grid, block, 0, stream>>>(in1, in2, out);
}

// Round 3
// 47.863 us; speedup vs baseline: 1.2785x; 1.0530x over previous
//
#include <hip/hip_runtime.h>

// Resample1d: out[b,c,h,w] = lerp of input1[b,c,h,:] at x = w + disp[b,h,w],
// zeroed where x outside [0, W-1].
// Shapes: input1 (B,C,H,W) f32, input2 (B,1,H,W) f32, out (B,C,H,W) f32.
//
// R3: gather-free global path. Each wave owns one (b,h) row x 8 channels:
//  - pixel params (i0,i1,w0,w1) computed once, hoisted across channels
//  - in1 row staged via coalesced float4 loads into wave-PRIVATE 2KB LDS
//    chunk (no __syncthreads needed; same-wave DS ops are ordered)
//  - taps become ds_read_b32 at ~stride-1 (2-way bank alias is free)
//  - 1-deep register prefetch overlaps next channel's global load w/ compute
//  - non-temporal stores keep the write stream from evicting in1 in L2/L3

#define B 4
#define C 64
#define H 256
#define W 512
#define WAVES 4          // waves per block
#define CPW 8            // channels per wave
// grid = (B*H, C/(WAVES*CPW)) = (1024, 2); block = 256

__global__ __launch_bounds__(256) void resample1d_kernel(
    const float* __restrict__ in1,   // (B,C,H,W)
    const float* __restrict__ in2,   // (B,1,H,W)
    float* __restrict__ out)         // (B,C,H,W)
{
    __shared__ float rowbuf[WAVES][W];   // 4 x 2KB = 8KB, wave-private chunks

    const int tid  = threadIdx.x;
    const int wid  = tid >> 6;
    const int lane = tid & 63;

    const int bh = blockIdx.x;          // 0..B*H-1
    const int b  = bh >> 8;             // / H  (H=256)
    const int h  = bh & (H - 1);
    const int cbase = blockIdx.y * (WAVES * CPW) + wid * CPW;

    // --- per-lane pixel params for 8 pixels: w = lane + 64*p (hoisted over c) ---
    const float* disp_row = in2 + (size_t)bh * W;
    int   i0[8], i1[8];
    float w0[8], w1[8];
    #pragma unroll
    for (int p = 0; p < 8; ++p) {
        int w = lane + 64 * p;
        float x = (float)w + disp_row[w];
        bool valid = (x >= 0.0f) && (x <= (float)(W - 1));
        float x0 = floorf(x);
        float frac = x - x0;
        float x0c = fminf(fmaxf(x0, 0.0f), (float)(W - 1));
        i0[p] = (int)x0c;
        i1[p] = min(i0[p] + 1, W - 1);
        w0[p] = valid ? (1.0f - frac) : 0.0f;
        w1[p] = valid ? frac : 0.0f;
    }

    float* rb = rowbuf[wid];

    const size_t chan_stride = (size_t)H * W;
    const float* src = in1 + ((size_t)b * C + cbase) * chan_stride + (size_t)h * W;
    float*       dst = out + ((size_t)b * C + cbase) * chan_stride + (size_t)h * W;

    // prologue: channel 0 row -> regs (coalesced float4, 16B/lane)
    float4 r0 = *(const float4*)(src + 4 * lane);
    float4 r1 = *(const float4*)(src + 256 + 4 * lane);

    #pragma unroll
    for (int cc = 0; cc < CPW; ++cc) {
        // staged regs -> wave-private LDS (ds_write_b128, conflict-free)
        *(float4*)(rb + 4 * lane)       = r0;
        *(float4*)(rb + 256 + 4 * lane) = r1;
        // issue next channel's global loads early (hide latency under compute)
        if (cc + 1 < CPW) {
            const float* s2 = src + (size_t)(cc + 1) * chan_stride;
            r0 = *(const float4*)(s2 + 4 * lane);
            r1 = *(const float4*)(s2 + 256 + 4 * lane);
        }
        // taps from LDS, lerp, coalesced NT stores
        float* d = dst + (size_t)cc * chan_stride;
        #pragma unroll
        for (int p = 0; p < 8; ++p) {
            float g0 = rb[i0[p]];
            float g1 = rb[i1[p]];
            __builtin_nontemporal_store(w0[p] * g0 + w1[p] * g1, d + lane + 64 * p);
        }
    }
}

extern "C" void kernel_launch(void* const* d_in, const int* in_sizes, int n_in,
                              void* d_out, int out_size, void* d_ws, size_t ws_size,
                              hipStream_t stream) {
    const float* in1 = (const float*)d_in[0];
    const float* in2 = (const float*)d_in[1];
    float* out = (float*)d_out;

    dim3 grid(B * H, C / (WAVES * CPW)), block(WAVES * 64);
    resample1d_kernel<<<grid, block, 0, stream>>>(in1, in2, out);
}

// Round 5
// 45.848 us; speedup vs baseline: 1.3347x; 1.0440x over previous
//
#include <hip/hip_runtime.h>

// Resample1d: out[b,c,h,w] = lerp of input1[b,c,h,:] at x = w + disp[b,h,w],
// zeroed where x outside [0, W-1].
// Shapes: input1 (B,C,H,W) f32, input2 (B,1,H,W) f32, out (B,C,H,W) f32.
//
// R5 = R4 with the compile fix: __builtin_nontemporal_store needs a clang
// ext_vector_type, not HIP's float4 struct.
//  - 2-deep prefetch ring: channels c+1,c+2 in flight (4 x 16B loads/wave)
//  - c0/c1 global loads issued BEFORE param computation (overlap)
//  - pixel mapping w = 4*lane + 256*g + j: disp read and stores are dwordx4
//  - i1 recomputed on the fly to keep VGPR low

#define B 4
#define C 64
#define H 256
#define W 512
#define WAVES 4          // waves per block
#define CPW 8            // channels per wave
// grid = (B*H, C/(WAVES*CPW)) = (1024, 2); block = 256

typedef float f32x4 __attribute__((ext_vector_type(4)));

__global__ __launch_bounds__(256) void resample1d_kernel(
    const float* __restrict__ in1,   // (B,C,H,W)
    const float* __restrict__ in2,   // (B,1,H,W)
    float* __restrict__ out)         // (B,C,H,W)
{
    __shared__ float rowbuf[WAVES][W];   // 4 x 2KB, wave-private chunks

    const int tid  = threadIdx.x;
    const int wid  = tid >> 6;
    const int lane = tid & 63;

    const int bh = blockIdx.x;          // 0..B*H-1
    const int b  = bh >> 8;             // / H  (H=256)
    const int cbase = blockIdx.y * (WAVES * CPW) + wid * CPW;

    const size_t chan_stride = (size_t)H * W;
    const float* src = in1 + ((size_t)b * C + cbase) * chan_stride + (size_t)(bh & (H - 1)) * W;
    float*       dst = out + ((size_t)b * C + cbase) * chan_stride + (size_t)(bh & (H - 1)) * W;
    const float* disp_row = in2 + (size_t)bh * W;

    // ---- issue first two channels' loads + disp loads up front ----
    f32x4 pre0[2], pre1[2];             // 2-deep prefetch ring (unrolled -> regs)
    pre0[0] = *(const f32x4*)(src + 4 * lane);
    pre1[0] = *(const f32x4*)(src + 256 + 4 * lane);
    pre0[1] = *(const f32x4*)(src + chan_stride + 4 * lane);
    pre1[1] = *(const f32x4*)(src + chan_stride + 256 + 4 * lane);
    f32x4 d4[2];
    d4[0] = *(const f32x4*)(disp_row + 4 * lane);
    d4[1] = *(const f32x4*)(disp_row + 256 + 4 * lane);

    // ---- per-lane pixel params: w = 4*lane + 256*g + j (hoisted over c) ----
    int   i0[2][4];
    float w0[2][4], w1[2][4];
    #pragma unroll
    for (int g = 0; g < 2; ++g) {
        #pragma unroll
        for (int j = 0; j < 4; ++j) {
            int w = 4 * lane + 256 * g + j;
            float x = (float)w + d4[g][j];
            bool valid = (x >= 0.0f) && (x <= (float)(W - 1));
            float x0 = floorf(x);
            float frac = x - x0;
            i0[g][j] = (int)fminf(fmaxf(x0, 0.0f), (float)(W - 1));
            w0[g][j] = valid ? (1.0f - frac) : 0.0f;
            w1[g][j] = valid ? frac : 0.0f;
        }
    }

    float* rb = rowbuf[wid];

    #pragma unroll
    for (int cc = 0; cc < CPW; ++cc) {
        // staged regs -> wave-private LDS (ds_write_b128, conflict-free)
        *(f32x4*)(rb + 4 * lane)       = pre0[cc & 1];
        *(f32x4*)(rb + 256 + 4 * lane) = pre1[cc & 1];
        // refill the ring slot just consumed (keeps 4 loads in flight)
        if (cc + 2 < CPW) {
            const float* s2 = src + (size_t)(cc + 2) * chan_stride;
            pre0[cc & 1] = *(const f32x4*)(s2 + 4 * lane);
            pre1[cc & 1] = *(const f32x4*)(s2 + 256 + 4 * lane);
        }
        // taps from LDS, lerp, two coalesced dwordx4 NT stores
        float* d = dst + (size_t)cc * chan_stride;
        #pragma unroll
        for (int g = 0; g < 2; ++g) {
            f32x4 r;
            #pragma unroll
            for (int j = 0; j < 4; ++j) {
                int a0 = i0[g][j];
                int a1 = min(a0 + 1, W - 1);
                r[j] = w0[g][j] * rb[a0] + w1[g][j] * rb[a1];
            }
            __builtin_nontemporal_store(r, (f32x4*)(d + 4 * lane + 256 * g));
        }
    }
}

extern "C" void kernel_launch(void* const* d_in, const int* in_sizes, int n_in,
                              void* d_out, int out_size, void* d_ws, size_t ws_size,
                              hipStream_t stream) {
    const float* in1 = (const float*)d_in[0];
    const float* in2 = (const float*)d_in[1];
    float* out = (float*)d_out;

    dim3 grid(B * H, C / (WAVES * CPW)), block(WAVES * 64);
    resample1d_kernel<<<grid, block, 0, stream>>>(in1, in2, out);
}